// Round 7
// baseline (223.077 us; speedup 1.0000x reference)
//
#include <hip/hip_runtime.h>
#include <cstdint>
#include <cstddef>

typedef unsigned short u16;
typedef short bf16x8 __attribute__((ext_vector_type(8)));
typedef float f32x4 __attribute__((ext_vector_type(4)));

#define MFMA(a,b,c) __builtin_amdgcn_mfma_f32_16x16x32_bf16(a,b,c,0,0,0)

__device__ __forceinline__ u16 f2bf(float f) {
  unsigned u = __builtin_bit_cast(unsigned, f);
  u += 0x7fffu + ((u >> 16) & 1u);
  return (u16)(u >> 16);
}
__device__ __forceinline__ float bf2f(u16 b) {
  return __builtin_bit_cast(float, (unsigned)b << 16);
}
__device__ __forceinline__ float exp2_hw(float x) {
  float r;
  asm("v_exp_f32 %0, %1" : "=v"(r) : "v"(x));
  return r;
}
__device__ __forceinline__ void gl_lds16(const void* g, void* l) {
  __builtin_amdgcn_global_load_lds(
      (const __attribute__((address_space(1))) void*)g,
      (__attribute__((address_space(3))) void*)l, 16, 0, 0);
}
template <int N>
__device__ __forceinline__ void wait_vmcnt() {
  if constexpr (N == 0) asm volatile("s_waitcnt vmcnt(0)" ::: "memory");
  else if constexpr (N == 2) asm volatile("s_waitcnt vmcnt(2)" ::: "memory");
  else if constexpr (N == 3) asm volatile("s_waitcnt vmcnt(3)" ::: "memory");
  else if constexpr (N == 4) asm volatile("s_waitcnt vmcnt(4)" ::: "memory");
}

// ---------------- fused f32 -> bf16 convert for all 5 inputs ----------------
__global__ __launch_bounds__(256) void cvt_all(const float* __restrict__ x,
                                               const float* __restrict__ wq,
                                               const float* __restrict__ wk,
                                               const float* __restrict__ wv,
                                               const float* __restrict__ wo,
                                               u16* __restrict__ xb,
                                               u16* __restrict__ wqkvb,
                                               u16* __restrict__ wob) {
  int idx = (blockIdx.x * 256 + threadIdx.x) * 4;
  const float* src;
  u16* dst;
  if (idx < 8388608) { src = x + idx; dst = xb + idx; }
  else if (idx < 12582912) { src = wq + (idx - 8388608); dst = wqkvb + (idx - 8388608); }
  else if (idx < 13631488) { src = wk + (idx - 12582912); dst = wqkvb + (idx - 8388608); }
  else if (idx < 14680064) { src = wv + (idx - 13631488); dst = wqkvb + (idx - 8388608); }
  else if (idx < 18874368) { src = wo + (idx - 14680064); dst = wob + (idx - 14680064); }
  else return;
  float4 v = *(const float4*)src;
  ushort4 o = {f2bf(v.x), f2bf(v.y), f2bf(v.z), f2bf(v.w)};
  *(ushort4*)dst = o;
}

// ---------------- RoPE cos/sin table: [T=2048][64] f32 ----------------
__global__ __launch_bounds__(256) void rope_table(float* __restrict__ ctab,
                                                  float* __restrict__ stab) {
  int i = blockIdx.x * 256 + threadIdx.x;  // 0 .. 131071
  int t = i >> 6, f = i & 63;
  float inv_freq = powf(10000.0f, -(2.0f * f) / 128.0f);
  float ang = (float)t * inv_freq;
  ctab[i] = cosf(ang);
  stab[i] = sinf(ang);
}

// ---------------- deep-pipelined NT GEMM v2 ----------------
// BK=32, 3-buffer LDS, 2-tiles-ahead staging, counted vmcnt, fragment reads
// software-pipelined one phase ahead so ds_read latency hides under MFMA.
// A[M,K] bf16 rm, B[N,K] bf16 rm -> C[M,N]. 512 threads (8 waves).
template <int BM, int BN, int OUT_F32>
__global__ __launch_bounds__(512, 2) void gemm8(const u16* __restrict__ A,
                                                const u16* __restrict__ Bw,
                                                void* __restrict__ Cout,
                                                int M, int N, int K) {
  constexpr int WN = BN / 64;           // waves along N (4 or 2)
  constexpr int WM = 8 / WN;            // waves along M (2 or 4)
  constexpr int M_SUB = BM / WM;        // rows per wave (128 or 64)
  constexpr int MF = M_SUB / 16;        // A frags per wave (8 or 4)
  constexpr int MH = MF / 2;            // half (4 or 2)
  constexpr int ACH = BM / 16;          // A chunks (1KB = 16 rows x 64B)
  constexpr int TCH = (BM + BN) / 16 / 8;  // chunks per wave per tile (4 or 3)
  constexpr int LPT = TCH;

  __shared__ u16 As[3][BM * 32];
  __shared__ u16 Bs[3][BN * 32];

  const int tid = threadIdx.x;
  const int lane = tid & 63;
  const int wv = tid >> 6;
  const int l16 = lane & 15, lhi = lane >> 4;
  const int wm = wv / WN, wn = wv % WN;
  const int m0 = blockIdx.y * BM;
  const int n0 = blockIdx.x * BN;
  const int nt = K >> 5;

  const int srow = lane >> 2;
  const int scolb = ((lane & 3) * 16) ^ ((((lane >> 3) & 3)) << 4);

  auto stage_chunk = [&](int buf, int kt, int c) {
    if (c < ACH) {
      const char* src = (const char*)A +
          ((size_t)(m0 + c * 16 + srow) * K + (size_t)kt * 32) * 2 + scolb;
      gl_lds16(src, (char*)As[buf] + c * 1024);
    } else {
      int cc = c - ACH;
      const char* src = (const char*)Bw +
          ((size_t)(n0 + cc * 16 + srow) * K + (size_t)kt * 32) * 2 + scolb;
      gl_lds16(src, (char*)Bs[buf] + cc * 1024);
    }
  };
  auto readA = [&](const u16* Ab, int mi) -> bf16x8 {
    int row = wm * M_SUB + mi * 16 + l16;
    return *(const bf16x8*)((const char*)Ab + row * 64 +
                            ((lhi * 16) ^ (((row >> 1) & 3) << 4)));
  };
  auto readB = [&](const u16* Bb, int ni) -> bf16x8 {
    int row = wn * 64 + ni * 16 + l16;
    return *(const bf16x8*)((const char*)Bb + row * 64 +
                            ((lhi * 16) ^ (((row >> 1) & 3) << 4)));
  };

  f32x4 acc[MF][4] = {};
  bf16x8 fB0[4], fB1[4], fA0[MH], fA1[MH];

  // prologue: stage tiles 0 and 1 fully
#pragma unroll
  for (int i = 0; i < TCH; ++i) stage_chunk(0, 0, wv + 8 * i);
#pragma unroll
  for (int i = 0; i < TCH; ++i) stage_chunk(1, 1, wv + 8 * i);
  wait_vmcnt<LPT>();          // tile0 retired; tile1 (LPT loads) in flight
  __builtin_amdgcn_sched_barrier(0);
  __builtin_amdgcn_s_barrier();
  __builtin_amdgcn_sched_barrier(0);
  // preload all fragments of tile 0
#pragma unroll
  for (int ni = 0; ni < 4; ++ni) fB0[ni] = readB(Bs[0], ni);
#pragma unroll
  for (int mi = 0; mi < MH; ++mi) fA0[mi] = readA(As[0], mi);
#pragma unroll
  for (int mi = 0; mi < MH; ++mi) fA1[mi] = readA(As[0], MH + mi);

  // tile body: computes tile t from frags {Bc, fA0, fA1}; prefetches t+1 frags
  // (B into Bn, A into fA0/fA1); stages t+2.
  auto tile_body = [&](int t, int p, bf16x8* Bc, bf16x8* Bn) {
    int pn = p + 1; if (pn == 3) pn = 0;
    int ps = pn + 1; if (ps == 3) ps = 0;
    const bool rd = (t + 1 < nt);
    const bool st = (t + 2 < nt);
    // s1: MFMA half0
    __builtin_amdgcn_s_setprio(1);
#pragma unroll
    for (int mi = 0; mi < MH; ++mi)
#pragma unroll
      for (int ni = 0; ni < 4; ++ni)
        acc[mi][ni] = MFMA(fA0[mi], Bc[ni], acc[mi][ni]);
    __builtin_amdgcn_s_setprio(0);
    // s2: stage first 2 chunks of t+2
    if (st) {
      stage_chunk(ps, t + 2, wv);
      stage_chunk(ps, t + 2, wv + 8);
    }
    // s3: counted gate -> buf t+1 ready
    if (rd) {
      if (st) wait_vmcnt<2>(); else wait_vmcnt<0>();
      __builtin_amdgcn_sched_barrier(0);
      __builtin_amdgcn_s_barrier();
      __builtin_amdgcn_sched_barrier(0);
      // s4: prefetch B + A-half0 of t+1
#pragma unroll
      for (int ni = 0; ni < 4; ++ni) Bn[ni] = readB(Bs[pn], ni);
#pragma unroll
      for (int mi = 0; mi < MH; ++mi) fA0[mi] = readA(As[pn], mi);
    }
    // s5: MFMA half1
    __builtin_amdgcn_s_setprio(1);
#pragma unroll
    for (int mi = 0; mi < MH; ++mi)
#pragma unroll
      for (int ni = 0; ni < 4; ++ni)
        acc[MH + mi][ni] = MFMA(fA1[mi], Bc[ni], acc[MH + mi][ni]);
    __builtin_amdgcn_s_setprio(0);
    // s6: stage remaining chunks of t+2
    if (st) {
#pragma unroll
      for (int i = 2; i < TCH; ++i) stage_chunk(ps, t + 2, wv + 8 * i);
    }
    // s7
    __builtin_amdgcn_sched_barrier(0);
    __builtin_amdgcn_s_barrier();
    __builtin_amdgcn_sched_barrier(0);
    // s8: prefetch A-half1 of t+1
    if (rd) {
#pragma unroll
      for (int mi = 0; mi < MH; ++mi) fA1[mi] = readA(As[pn], MH + mi);
    }
  };

  int pc = 0;
  for (int t = 0; t < nt; t += 2) {
    tile_body(t, pc, fB0, fB1);
    int p1 = pc + 1; if (p1 == 3) p1 = 0;
    tile_body(t + 1, p1, fB1, fB0);
    pc = p1 + 1; if (pc == 3) pc = 0;
  }

  // epilogue
#pragma unroll
  for (int mi = 0; mi < MF; ++mi)
#pragma unroll
    for (int ni = 0; ni < 4; ++ni) {
      int col = n0 + wn * 64 + ni * 16 + l16;
#pragma unroll
      for (int j = 0; j < 4; ++j) {
        int row = m0 + wm * M_SUB + mi * 16 + lhi * 4 + j;
        float v = acc[mi][ni][j];
        if (OUT_F32)
          ((float*)Cout)[(size_t)row * N + col] = v;
        else
          ((u16*)Cout)[(size_t)row * N + col] = f2bf(v);
      }
    }
}

// ---------------- RoPE + L2 norm + gamma ----------------
template <int NH>
__global__ __launch_bounds__(256) void rope_norm(const u16* __restrict__ raw,
                                                 u16* __restrict__ out,
                                                 const float* __restrict__ ctab,
                                                 const float* __restrict__ stab,
                                                 const float* __restrict__ gamma,
                                                 int stride, int coloff, float scale) {
  int gw = blockIdx.x * 4 + (threadIdx.x >> 6);
  int lane = threadIdx.x & 63;
  int h = gw & (NH - 1);
  int bt = gw / NH;               // 0..4095
  int t = bt & 2047, b = bt >> 11;
  const u16* r = raw + (size_t)bt * stride + coloff + (size_t)h * 128;
  float q1 = bf2f(r[lane]), q2 = bf2f(r[lane + 64]);
  float c = ctab[t * 64 + lane], s = stab[t * 64 + lane];
  float e1 = q1 * c - q2 * s;
  float e2 = q2 * c + q1 * s;
  float ss = e1 * e1 + e2 * e2;
#pragma unroll
  for (int off = 1; off < 64; off <<= 1) ss += __shfl_xor(ss, off);
  float inv = scale / (sqrtf(ss) + 1e-6f);
  size_t ob = (((size_t)(b * NH + h)) * 2048 + t) * 128;
  out[ob + lane]      = f2bf(e1 * inv * gamma[lane]);
  out[ob + lane + 64] = f2bf(e2 * inv * gamma[lane + 64]);
}

// ---------------- V transpose: qkv[B*T,3072] cols 2560.. -> [B, HK, 128, T] ----------------
__global__ __launch_bounds__(256) void transpose_v(const u16* __restrict__ qkv,
                                                   u16* __restrict__ vt) {
  __shared__ u16 tile[32][33];
  int t0 = blockIdx.x * 32, d0 = blockIdx.y * 32;
  int bh = blockIdx.z;
  int b = bh >> 2, hkk = bh & 3;
  int tx = threadIdx.x & 31, ty = threadIdx.x >> 5;  // ty 0..7
#pragma unroll
  for (int i = 0; i < 4; ++i) {
    int r = ty + i * 8;
    tile[r][tx] = qkv[((size_t)(b * 2048 + t0 + r)) * 3072 + 2560 + hkk * 128 + d0 + tx];
  }
  __syncthreads();
#pragma unroll
  for (int i = 0; i < 4; ++i) {
    int r = ty + i * 8;
    vt[((size_t)((b * 4 + hkk) * 128 + d0 + r)) * 2048 + t0 + tx] = tile[tx][r];
  }
}

// ---------------- flash attention, sliding window 1024, QBLK=128, KVBLK=64 ----------------
// 8 waves/block (512 thr), K+V double-buffered (swizzled) in LDS, log2-domain softmax
// with wave-shared base, rowsum via ones-MFMA, XCD-aware block remap.
__global__ __launch_bounds__(512, 4) void attn_kernel(const u16* __restrict__ Qr,
                                                      const u16* __restrict__ Kr,
                                                      const u16* __restrict__ Vt,
                                                      u16* __restrict__ Yt) {
  __shared__ u16 Ks[2][64 * 128];   // XOR-swizzled 256B rows (2x16KB)
  __shared__ u16 Vs[2][128 * 64];   // XOR-swizzled 128B rows, [d][s] (2x16KB)
  __shared__ u16 Ps[8][16 * 64];    // per-wave P, XOR-swizzled 128B rows (16KB)
  const int tid = threadIdx.x;
  const int lane = tid & 63;
  const int wv = tid >> 6;          // 0..7
  const int l16 = lane & 15, lhi = lane >> 4;
  const int work = (blockIdx.x & 7) * 64 + (blockIdx.x >> 3);
  const int q0b = (work & 15) << 7;     // q-tile * 128
  const int bh = work >> 4;             // 0..31
  const int b = bh >> 4, h = bh & 15;
  const int hk = h >> 2;
  const int q0w = q0b + wv * 16;

  const u16* qbase = Qr + (((size_t)bh) * 2048 + q0w + l16) * 128;
  bf16x8 qf[4];
#pragma unroll
  for (int dc = 0; dc < 4; ++dc)
    qf[dc] = *(const bf16x8*)(qbase + dc * 32 + lhi * 8);

  const char* kg = (const char*)(Kr + ((size_t)(b * 4 + hk)) * 2048 * 128);
  const u16* vg = Vt + ((size_t)(b * 4 + hk)) * 2048 * 128;  // [128][2048]

  auto stage = [&](int buf, int s0) {
#pragma unroll
    for (int i = 0; i < 2; ++i) {
      int c = wv + 8 * i;
      int row = c * 4 + lhi;
      int srcb = (l16 * 16) ^ ((row & 7) << 4);
      gl_lds16(kg + (size_t)(s0 + row) * 256 + srcb, (char*)Ks[buf] + c * 1024);
    }
    int r8 = lane >> 3, c8 = lane & 7;
#pragma unroll
    for (int i = 0; i < 2; ++i) {
      int c = wv + 8 * i;
      int row = c * 8 + r8;
      int srcb = (c8 * 16) ^ ((r8 & 7) << 4);
      gl_lds16((const char*)(vg + (size_t)row * 2048 + s0) + srcb,
               (char*)Vs[buf] + c * 1024);
    }
  };

  const bf16x8 ones = {0x3F80, 0x3F80, 0x3F80, 0x3F80, 0x3F80, 0x3F80, 0x3F80, 0x3F80};
  float mbase = 0.f;                // wave-shared log2-domain base
  f32x4 lacc = {};
  f32x4 oacc[8] = {};

  int s_lo = q0b - 1024; if (s_lo < 0) s_lo = 0;
  const int nt = (q0b + 128 - s_lo) >> 6;

  stage(0, s_lo);
  __syncthreads();
  int cur = 0;
  for (int it = 0; it < nt; ++it) {
    const int s0 = s_lo + (it << 6);
    if (it + 1 < nt) stage(cur ^ 1, s0 + 64);
    const bool skip = (q0w + 15 < s0) || (q0w - (s0 + 63) > 1024);
    if (!skip) {
      // QK^T (16 MFMA)
      f32x4 sacc[4] = {};
      const char* ksb = (const char*)Ks[cur];
      __builtin_amdgcn_s_setprio(1);
#pragma unroll
      for (int n = 0; n < 4; ++n) {
        int row = n * 16 + l16;
#pragma unroll
        for (int dc = 0; dc < 4; ++dc) {
          bf16x8 kf = *(const bf16x8*)(ksb + row * 256 +
                                       ((dc * 64 + lhi * 16) ^ ((l16 & 7) << 4)));
          sacc[n] = MFMA(qf[dc], kf, sacc[n]);
        }
      }
      __builtin_amdgcn_s_setprio(0);
      const bool domask = (q0w < s0 + 63) || (q0w + 15 - s0 > 1024);
      if (domask) {
#pragma unroll
        for (int n = 0; n < 4; ++n)
#pragma unroll
          for (int j = 0; j < 4; ++j) {
            int q = q0w + lhi * 4 + j;
            int s = s0 + n * 16 + l16;
            if ((unsigned)(q - s) > 1024u) sacc[n][j] = -INFINITY;
          }
      }
      float mt = sacc[0][0];
#pragma unroll
      for (int n = 0; n < 4; ++n)
#pragma unroll
        for (int j = 0; j < 4; ++j) mt = fmaxf(mt, sacc[n][j]);
#pragma unroll
      for (int off = 1; off < 64; off <<= 1) mt = fmaxf(mt, __shfl_xor(mt, off));
      if (mt > mbase + 8.f) {
        float sc2 = exp2_hw(mbase - mt);
#pragma unroll
        for (int j = 0; j < 4; ++j) lacc[j] *= sc2;
#pragma unroll
        for (int dt = 0; dt < 8; ++dt)
#pragma unroll
          for (int j = 0; j < 4; ++j) oacc[dt][j] *= sc2;
        mbase = mt;
      }
      char* psb = (char*)Ps[wv];
#pragma unroll
      for (int n = 0; n < 4; ++n)
#pragma unroll
        for (int j = 0; j < 4; ++j) {
          float p = exp2_hw(sacc[n][j] - mbase);
          int R = lhi * 4 + j;
          *(u16*)(psb + R * 128 + (((n * 16 + l16) * 2) ^ ((R & 7) << 4))) = f2bf(p);
        }
      bf16x8 pf[2];
#pragma unroll
      for (int kk = 0; kk < 2; ++kk)
        pf[kk] = *(const bf16x8*)(psb + l16 * 128 +
                                  ((kk * 64 + lhi * 16) ^ ((l16 & 7) << 4)));
      const char* vsb = (const char*)Vs[cur];
      __builtin_amdgcn_s_setprio(1);
      lacc = MFMA(pf[0], ones, lacc);
      lacc = MFMA(pf[1], ones, lacc);
#pragma unroll
      for (int dt = 0; dt < 8; ++dt) {
        int row = dt * 16 + l16;
#pragma unroll
        for (int kk = 0; kk < 2; ++kk) {
          bf16x8 vf = *(const bf16x8*)(vsb + row * 128 +
                                       ((kk * 64 + lhi * 16) ^ ((l16 & 7) << 4)));
          oacc[dt] = MFMA(pf[kk], vf, oacc[dt]);
        }
      }
      __builtin_amdgcn_s_setprio(0);
    }
    __syncthreads();
    cur ^= 1;
  }
#pragma unroll
  for (int j = 0; j < 4; ++j) {
    float inv = 1.0f / lacc[j];
    int q = q0w + lhi * 4 + j;
    size_t rowbase = ((size_t)(b * 2048 + q)) * 2048 + (size_t)h * 128;
#pragma unroll
    for (int dt = 0; dt < 8; ++dt)
      Yt[rowbase + dt * 16 + l16] = f2bf(oacc[dt][j] * inv);
  }
}

extern "C" void kernel_launch(void* const* d_in, const int* in_sizes, int n_in,
                              void* d_out, int out_size, void* d_ws, size_t ws_size,
                              hipStream_t stream) {
  (void)in_sizes; (void)n_in; (void)out_size; (void)ws_size;
  const float* x  = (const float*)d_in[0];
  const float* wq = (const float*)d_in[1];
  const float* wk = (const float*)d_in[2];
  const float* wv = (const float*)d_in[3];
  const float* wo = (const float*)d_in[4];
  const float* gq = (const float*)d_in[5];
  const float* gk = (const float*)d_in[6];
  float* out = (float*)d_out;
  char* ws = (char*)d_ws;

  size_t off = 0;
  auto alloc = [&](size_t bytes) {
    size_t o = off;
    off += (bytes + 255) & ~(size_t)255;
    return o;
  };
  u16* xb     = (u16*)(ws + alloc((size_t)4096 * 2048 * 2));
  u16* wqkvb  = (u16*)(ws + alloc((size_t)3072 * 2048 * 2));
  u16* wob    = (u16*)(ws + alloc((size_t)2048 * 2048 * 2));
  u16* qkvraw = (u16*)(ws + alloc((size_t)4096 * 3072 * 2));  // later reused as ytmp
  u16* qr     = (u16*)(ws + alloc((size_t)4096 * 2048 * 2));
  u16* kr     = (u16*)(ws + alloc((size_t)4096 * 512 * 2));
  u16* vt     = (u16*)(ws + alloc((size_t)4096 * 512 * 2));
  float* ctab = (float*)(ws + alloc((size_t)2048 * 64 * 4));
  float* stab = (float*)(ws + alloc((size_t)2048 * 64 * 4));
  u16* ytmp = qkvraw;  // safe: qkvraw fully consumed before attn writes

  // 1/sqrt(128) * log2(e): Q scale folded so scores are in log2 domain
  const float sc_log2 = 0.12751744f;

  cvt_all<<<18432, 256, 0, stream>>>(x, wq, wk, wv, wo, xb, wqkvb, wob);
  rope_table<<<512, 256, 0, stream>>>(ctab, stab);

  // fused QKV projection: [4096,2048] x [3072,2048]^T -> [4096,3072]
  gemm8<256, 256, 0><<<dim3(12, 16), 512, 0, stream>>>(xb, wqkvb, qkvraw, 4096, 3072, 2048);

  rope_norm<16><<<16384, 256, 0, stream>>>(qkvraw, qr, ctab, stab, gq, 3072, 0, sc_log2);
  rope_norm<4><<<4096, 256, 0, stream>>>(qkvraw, kr, ctab, stab, gk, 3072, 2048, 1.0f);
  transpose_v<<<dim3(64, 4, 8), 256, 0, stream>>>(qkvraw, vt);

  attn_kernel<<<dim3(512), 512, 0, stream>>>(qr, kr, vt, ytmp);

  // output projection (f32 out): 256x128 tiles -> 256 blocks (1/CU)
  gemm8<256, 128, 1><<<dim3(16, 16), 512, 0, stream>>>(ytmp, wob, out, 4096, 2048, 2048);
}

// Round 8
// 211.623 us; speedup vs baseline: 1.0541x; 1.0541x over previous
//
#include <hip/hip_runtime.h>
#include <cstdint>
#include <cstddef>

typedef unsigned short u16;
typedef short bf16x8 __attribute__((ext_vector_type(8)));
typedef float f32x4 __attribute__((ext_vector_type(4)));

#define MFMA(a,b,c) __builtin_amdgcn_mfma_f32_16x16x32_bf16(a,b,c,0,0,0)

__device__ __forceinline__ u16 f2bf(float f) {
  unsigned u = __builtin_bit_cast(unsigned, f);
  u += 0x7fffu + ((u >> 16) & 1u);
  return (u16)(u >> 16);
}
__device__ __forceinline__ float bf2f(u16 b) {
  return __builtin_bit_cast(float, (unsigned)b << 16);
}
__device__ __forceinline__ float exp2_hw(float x) {
  float r;
  asm("v_exp_f32 %0, %1" : "=v"(r) : "v"(x));
  return r;
}
__device__ __forceinline__ void gl_lds16(const void* g, void* l) {
  __builtin_amdgcn_global_load_lds(
      (const __attribute__((address_space(1))) void*)g,
      (__attribute__((address_space(3))) void*)l, 16, 0, 0);
}
template <int N>
__device__ __forceinline__ void wait_vmcnt() {
  if constexpr (N == 0) asm volatile("s_waitcnt vmcnt(0)" ::: "memory");
  else if constexpr (N == 8) asm volatile("s_waitcnt vmcnt(8)" ::: "memory");
}

// ---------------- fused f32 -> bf16 convert for all 5 inputs ----------------
__global__ __launch_bounds__(256) void cvt_all(const float* __restrict__ x,
                                               const float* __restrict__ wq,
                                               const float* __restrict__ wk,
                                               const float* __restrict__ wv,
                                               const float* __restrict__ wo,
                                               u16* __restrict__ xb,
                                               u16* __restrict__ wqkvb,
                                               u16* __restrict__ wob) {
  int idx = (blockIdx.x * 256 + threadIdx.x) * 4;
  const float* src;
  u16* dst;
  if (idx < 8388608) { src = x + idx; dst = xb + idx; }
  else if (idx < 12582912) { src = wq + (idx - 8388608); dst = wqkvb + (idx - 8388608); }
  else if (idx < 13631488) { src = wk + (idx - 12582912); dst = wqkvb + (idx - 8388608); }
  else if (idx < 14680064) { src = wv + (idx - 13631488); dst = wqkvb + (idx - 8388608); }
  else if (idx < 18874368) { src = wo + (idx - 14680064); dst = wob + (idx - 14680064); }
  else return;
  float4 v = *(const float4*)src;
  ushort4 o = {f2bf(v.x), f2bf(v.y), f2bf(v.z), f2bf(v.w)};
  *(ushort4*)dst = o;
}

// ---------------- RoPE cos/sin table: [T=2048][64] f32 ----------------
__global__ __launch_bounds__(256) void rope_table(float* __restrict__ ctab,
                                                  float* __restrict__ stab) {
  int i = blockIdx.x * 256 + threadIdx.x;  // 0 .. 131071
  int t = i >> 6, f = i & 63;
  float inv_freq = powf(10000.0f, -(2.0f * f) / 128.0f);
  float ang = (float)t * inv_freq;
  ctab[i] = cosf(ang);
  stab[i] = sinf(ang);
}

// ---------------- deep-pipelined NT GEMM: 256x256 tile, BK=64 ----------------
// 2 LDS buffers (one full K-tile each, 128KB), 8 waves each 128x64 output.
// Per K-tile: 2x32-MFMA clusters, 2 barriers, 1 counted vmcnt(8) (never 0 mid-loop).
// Stage of tile t+2 overwrites the buffer of tile t right after all reads landed.
template <int OUT_F32>
__global__ __launch_bounds__(512, 2) void gemm8p(const u16* __restrict__ A,
                                                 const u16* __restrict__ Bw,
                                                 void* __restrict__ Cout,
                                                 int M, int N, int K) {
  __shared__ u16 As[2][2][128 * 64];  // [buf][half][row*64+col] 128B rows
  __shared__ u16 Bs[2][2][128 * 64];
  const int tid = threadIdx.x;
  const int lane = tid & 63;
  const int wv = tid >> 6;          // 0..7
  const int l16 = lane & 15, lhi = lane >> 4;
  const int wm = wv >> 2, wn = wv & 3;   // 2 x 4 wave grid
  const int m0 = blockIdx.y * 256;
  const int n0 = blockIdx.x * 256;
  const int nt = K >> 6;

  const int srow8 = lane >> 3;                       // dest row within chunk (0..7)
  const int scol = ((lane & 7) * 16) ^ (srow8 << 4); // pre-swizzled source col byte

  auto stage_tile = [&](int buf, int kt) {
    // A: 2 halves x 16 chunks(1KB=8 rows); wave does chunks wv, wv+8 per half
#pragma unroll
    for (int h = 0; h < 2; ++h)
#pragma unroll
      for (int s = 0; s < 2; ++s) {
        int ch = wv + 8 * s;
        int row = m0 + h * 128 + ch * 8 + srow8;
        const char* src = (const char*)A + ((size_t)row * K + (size_t)kt * 64) * 2 + scol;
        gl_lds16(src, (char*)As[buf][h] + ch * 1024);
      }
#pragma unroll
    for (int h = 0; h < 2; ++h)
#pragma unroll
      for (int s = 0; s < 2; ++s) {
        int ch = wv + 8 * s;
        int row = n0 + h * 128 + ch * 8 + srow8;
        const char* src = (const char*)Bw + ((size_t)row * K + (size_t)kt * 64) * 2 + scol;
        gl_lds16(src, (char*)Bs[buf][h] + ch * 1024);
      }
  };
  // LDS[r][s] = G[r][s^(r&7)] (16B slots); read slot_g=kk*4+lhi with XOR (l16&7)
  auto readA = [&](int buf, int mi, int kk) -> bf16x8 {
    int lr = mi * 16 + l16;
    return *(const bf16x8*)((const char*)As[buf][wm] + lr * 128 +
                            ((kk * 64 + lhi * 16) ^ ((l16 & 7) << 4)));
  };
  auto readB = [&](int buf, int ni, int kk) -> bf16x8 {
    int lr = (wn & 1) * 64 + ni * 16 + l16;
    return *(const bf16x8*)((const char*)Bs[buf][wn >> 1] + lr * 128 +
                            ((kk * 64 + lhi * 16) ^ ((l16 & 7) << 4)));
  };

  f32x4 acc[8][4] = {};

  stage_tile(0, 0);
  stage_tile(1, 1);
  wait_vmcnt<8>();                 // tile0 landed; tile1's 8 loads in flight
  __builtin_amdgcn_sched_barrier(0);
  __builtin_amdgcn_s_barrier();
  __builtin_amdgcn_sched_barrier(0);

  for (int t = 0; t < nt; ++t) {
    const int b = t & 1;
    // ---- P0: read kk0 frags, 32 MFMA ----
    bf16x8 bf0[4], af0[8];
#pragma unroll
    for (int ni = 0; ni < 4; ++ni) bf0[ni] = readB(b, ni, 0);
#pragma unroll
    for (int mi = 0; mi < 8; ++mi) af0[mi] = readA(b, mi, 0);
    __builtin_amdgcn_s_setprio(1);
#pragma unroll
    for (int mi = 0; mi < 8; ++mi)
#pragma unroll
      for (int ni = 0; ni < 4; ++ni)
        acc[mi][ni] = MFMA(af0[mi], bf0[ni], acc[mi][ni]);
    __builtin_amdgcn_s_setprio(0);
    // ---- P1: read kk1 frags, fence, stage t+2 over buf b, 32 MFMA ----
    bf16x8 bf1[4], af1[8];
#pragma unroll
    for (int ni = 0; ni < 4; ++ni) bf1[ni] = readB(b, ni, 1);
#pragma unroll
    for (int mi = 0; mi < 8; ++mi) af1[mi] = readA(b, mi, 1);
    asm volatile("s_waitcnt lgkmcnt(0)" ::: "memory");  // all buf-b reads in regs
    __builtin_amdgcn_sched_barrier(0);
    __builtin_amdgcn_s_barrier();                        // all waves done reading buf b
    __builtin_amdgcn_sched_barrier(0);
    if (t + 2 < nt) stage_tile(b, t + 2);                // safe overwrite
    __builtin_amdgcn_s_setprio(1);
#pragma unroll
    for (int mi = 0; mi < 8; ++mi)
#pragma unroll
      for (int ni = 0; ni < 4; ++ni)
        acc[mi][ni] = MFMA(af1[mi], bf1[ni], acc[mi][ni]);
    __builtin_amdgcn_s_setprio(0);
    if (t + 2 < nt) wait_vmcnt<8>();        // retire tile t+1; t+2 stays in flight
    else if (t + 1 < nt) wait_vmcnt<0>();   // tail: tile t+1 must land
    __builtin_amdgcn_sched_barrier(0);
    __builtin_amdgcn_s_barrier();
    __builtin_amdgcn_sched_barrier(0);
  }

  // epilogue
#pragma unroll
  for (int mi = 0; mi < 8; ++mi)
#pragma unroll
    for (int ni = 0; ni < 4; ++ni) {
      int col = n0 + wn * 64 + ni * 16 + l16;
#pragma unroll
      for (int j = 0; j < 4; ++j) {
        int row = m0 + wm * 128 + mi * 16 + lhi * 4 + j;
        float v = acc[mi][ni][j];
        if (OUT_F32)
          ((float*)Cout)[(size_t)row * N + col] = v;
        else
          ((u16*)Cout)[(size_t)row * N + col] = f2bf(v);
      }
    }
}

// ---------------- RoPE + L2 norm + gamma (vectorized: 4B/lane) ----------------
template <int NH>
__global__ __launch_bounds__(256) void rope_norm(const u16* __restrict__ raw,
                                                 u16* __restrict__ out,
                                                 const float* __restrict__ ctab,
                                                 const float* __restrict__ stab,
                                                 const float* __restrict__ gamma,
                                                 int stride, int coloff, float scale) {
  int gw = blockIdx.x * 4 + (threadIdx.x >> 6);
  int lane = threadIdx.x & 63;
  int h = gw & (NH - 1);
  int bt = gw / NH;               // 0..4095
  int t = bt & 2047, bb = bt >> 11;
  const u16* r = raw + (size_t)bt * stride + coloff + (size_t)h * 128;
  // lane owns elements {2*lane, 2*lane+1}; partner lane^32 holds the rope pair
  ushort2 own = *(const ushort2*)(r + 2 * lane);
  int pk = __shfl_xor(__builtin_bit_cast(int, own), 32);
  ushort2 par = __builtin_bit_cast(ushort2, pk);
  float x0 = bf2f(own.x), x1 = bf2f(own.y);
  float y0 = bf2f(par.x), y1 = bf2f(par.y);
  int f = (lane & 31) * 2;
  float2 c2 = *(const float2*)(ctab + t * 64 + f);
  float2 s2 = *(const float2*)(stab + t * 64 + f);
  bool hi = lane >= 32;
  float e0 = hi ? (x0 * c2.x + y0 * s2.x) : (x0 * c2.x - y0 * s2.x);
  float e1 = hi ? (x1 * c2.y + y1 * s2.y) : (x1 * c2.y - y1 * s2.y);
  float ss = e0 * e0 + e1 * e1;
#pragma unroll
  for (int off = 1; off < 64; off <<= 1) ss += __shfl_xor(ss, off);
  float inv = scale / (sqrtf(ss) + 1e-6f);
  float2 g2 = *(const float2*)(gamma + 2 * lane);
  size_t ob = (((size_t)(bb * NH + h)) * 2048 + t) * 128 + 2 * lane;
  ushort2 o = {f2bf(e0 * inv * g2.x), f2bf(e1 * inv * g2.y)};
  *(ushort2*)(out + ob) = o;
}

// ---------------- V transpose: qkv[B*T,3072] cols 2560.. -> [B, HK, 128, T] ----------------
__global__ __launch_bounds__(256) void transpose_v(const u16* __restrict__ qkv,
                                                   u16* __restrict__ vt) {
  __shared__ u16 tile[32][33];
  int t0 = blockIdx.x * 32, d0 = blockIdx.y * 32;
  int bh = blockIdx.z;
  int b = bh >> 2, hkk = bh & 3;
  int tx = threadIdx.x & 31, ty = threadIdx.x >> 5;  // ty 0..7
#pragma unroll
  for (int i = 0; i < 4; ++i) {
    int r = ty + i * 8;
    tile[r][tx] = qkv[((size_t)(b * 2048 + t0 + r)) * 3072 + 2560 + hkk * 128 + d0 + tx];
  }
  __syncthreads();
#pragma unroll
  for (int i = 0; i < 4; ++i) {
    int r = ty + i * 8;
    vt[((size_t)((b * 4 + hkk) * 128 + d0 + r)) * 2048 + t0 + tx] = tile[tx][r];
  }
}

// ---------------- flash attention, sliding window 1024, QBLK=128, KVBLK=64 ----------------
// 8 waves/block (512 thr), K+V double-buffered (swizzled) in LDS, log2-domain softmax
// with wave-shared base, rowsum via ones-MFMA, XCD-aware block remap.
__global__ __launch_bounds__(512, 4) void attn_kernel(const u16* __restrict__ Qr,
                                                      const u16* __restrict__ Kr,
                                                      const u16* __restrict__ Vt,
                                                      u16* __restrict__ Yt) {
  __shared__ u16 Ks[2][64 * 128];   // XOR-swizzled 256B rows (2x16KB)
  __shared__ u16 Vs[2][128 * 64];   // XOR-swizzled 128B rows, [d][s] (2x16KB)
  __shared__ u16 Ps[8][16 * 64];    // per-wave P, XOR-swizzled 128B rows (16KB)
  const int tid = threadIdx.x;
  const int lane = tid & 63;
  const int wv = tid >> 6;          // 0..7
  const int l16 = lane & 15, lhi = lane >> 4;
  const int work = (blockIdx.x & 7) * 64 + (blockIdx.x >> 3);
  const int q0b = (work & 15) << 7;     // q-tile * 128
  const int bh = work >> 4;             // 0..31
  const int b = bh >> 4, h = bh & 15;
  const int hk = h >> 2;
  const int q0w = q0b + wv * 16;

  const u16* qbase = Qr + (((size_t)bh) * 2048 + q0w + l16) * 128;
  bf16x8 qf[4];
#pragma unroll
  for (int dc = 0; dc < 4; ++dc)
    qf[dc] = *(const bf16x8*)(qbase + dc * 32 + lhi * 8);

  const char* kg = (const char*)(Kr + ((size_t)(b * 4 + hk)) * 2048 * 128);
  const u16* vg = Vt + ((size_t)(b * 4 + hk)) * 2048 * 128;  // [128][2048]

  auto stage = [&](int buf, int s0) {
#pragma unroll
    for (int i = 0; i < 2; ++i) {
      int c = wv + 8 * i;
      int row = c * 4 + lhi;
      int srcb = (l16 * 16) ^ ((row & 7) << 4);
      gl_lds16(kg + (size_t)(s0 + row) * 256 + srcb, (char*)Ks[buf] + c * 1024);
    }
    int r8 = lane >> 3, c8 = lane & 7;
#pragma unroll
    for (int i = 0; i < 2; ++i) {
      int c = wv + 8 * i;
      int row = c * 8 + r8;
      int srcb = (c8 * 16) ^ ((r8 & 7) << 4);
      gl_lds16((const char*)(vg + (size_t)row * 2048 + s0) + srcb,
               (char*)Vs[buf] + c * 1024);
    }
  };

  const bf16x8 ones = {0x3F80, 0x3F80, 0x3F80, 0x3F80, 0x3F80, 0x3F80, 0x3F80, 0x3F80};
  float mbase = 0.f;                // wave-shared log2-domain base
  f32x4 lacc = {};
  f32x4 oacc[8] = {};

  int s_lo = q0b - 1024; if (s_lo < 0) s_lo = 0;
  const int nt = (q0b + 128 - s_lo) >> 6;

  stage(0, s_lo);
  __syncthreads();
  int cur = 0;
  for (int it = 0; it < nt; ++it) {
    const int s0 = s_lo + (it << 6);
    if (it + 1 < nt) stage(cur ^ 1, s0 + 64);
    const bool skip = (q0w + 15 < s0) || (q0w - (s0 + 63) > 1024);
    if (!skip) {
      // QK^T (16 MFMA)
      f32x4 sacc[4] = {};
      const char* ksb = (const char*)Ks[cur];
      __builtin_amdgcn_s_setprio(1);
#pragma unroll
      for (int n = 0; n < 4; ++n) {
        int row = n * 16 + l16;
#pragma unroll
        for (int dc = 0; dc < 4; ++dc) {
          bf16x8 kf = *(const bf16x8*)(ksb + row * 256 +
                                       ((dc * 64 + lhi * 16) ^ ((l16 & 7) << 4)));
          sacc[n] = MFMA(qf[dc], kf, sacc[n]);
        }
      }
      __builtin_amdgcn_s_setprio(0);
      const bool domask = (q0w < s0 + 63) || (q0w + 15 - s0 > 1024);
      if (domask) {
#pragma unroll
        for (int n = 0; n < 4; ++n)
#pragma unroll
          for (int j = 0; j < 4; ++j) {
            int q = q0w + lhi * 4 + j;
            int s = s0 + n * 16 + l16;
            if ((unsigned)(q - s) > 1024u) sacc[n][j] = -INFINITY;
          }
      }
      float mt = sacc[0][0];
#pragma unroll
      for (int n = 0; n < 4; ++n)
#pragma unroll
        for (int j = 0; j < 4; ++j) mt = fmaxf(mt, sacc[n][j]);
#pragma unroll
      for (int off = 1; off < 64; off <<= 1) mt = fmaxf(mt, __shfl_xor(mt, off));
      if (mt > mbase + 8.f) {
        float sc2 = exp2_hw(mbase - mt);
#pragma unroll
        for (int j = 0; j < 4; ++j) lacc[j] *= sc2;
#pragma unroll
        for (int dt = 0; dt < 8; ++dt)
#pragma unroll
          for (int j = 0; j < 4; ++j) oacc[dt][j] *= sc2;
        mbase = mt;
      }
      char* psb = (char*)Ps[wv];
#pragma unroll
      for (int n = 0; n < 4; ++n)
#pragma unroll
        for (int j = 0; j < 4; ++j) {
          float p = exp2_hw(sacc[n][j] - mbase);
          int R = lhi * 4 + j;
          *(u16*)(psb + R * 128 + (((n * 16 + l16) * 2) ^ ((R & 7) << 4))) = f2bf(p);
        }
      bf16x8 pf[2];
#pragma unroll
      for (int kk = 0; kk < 2; ++kk)
        pf[kk] = *(const bf16x8*)(psb + l16 * 128 +
                                  ((kk * 64 + lhi * 16) ^ ((l16 & 7) << 4)));
      const char* vsb = (const char*)Vs[cur];
      __builtin_amdgcn_s_setprio(1);
      lacc = MFMA(pf[0], ones, lacc);
      lacc = MFMA(pf[1], ones, lacc);
#pragma unroll
      for (int dt = 0; dt < 8; ++dt) {
        int row = dt * 16 + l16;
#pragma unroll
        for (int kk = 0; kk < 2; ++kk) {
          bf16x8 vf = *(const bf16x8*)(vsb + row * 128 +
                                       ((kk * 64 + lhi * 16) ^ ((l16 & 7) << 4)));
          oacc[dt] = MFMA(pf[kk], vf, oacc[dt]);
        }
      }
      __builtin_amdgcn_s_setprio(0);
    }
    __syncthreads();
    cur ^= 1;
  }
#pragma unroll
  for (int j = 0; j < 4; ++j) {
    float inv = 1.0f / lacc[j];
    int q = q0w + lhi * 4 + j;
    size_t rowbase = ((size_t)(b * 2048 + q)) * 2048 + (size_t)h * 128;
#pragma unroll
    for (int dt = 0; dt < 8; ++dt)
      Yt[rowbase + dt * 16 + l16] = f2bf(oacc[dt][j] * inv);
  }
}

extern "C" void kernel_launch(void* const* d_in, const int* in_sizes, int n_in,
                              void* d_out, int out_size, void* d_ws, size_t ws_size,
                              hipStream_t stream) {
  (void)in_sizes; (void)n_in; (void)out_size; (void)ws_size;
  const float* x  = (const float*)d_in[0];
  const float* wq = (const float*)d_in[1];
  const float* wk = (const float*)d_in[2];
  const float* wv = (const float*)d_in[3];
  const float* wo = (const float*)d_in[4];
  const float* gq = (const float*)d_in[5];
  const float* gk = (const float*)d_in[6];
  float* out = (float*)d_out;
  char* ws = (char*)d_ws;

  size_t off = 0;
  auto alloc = [&](size_t bytes) {
    size_t o = off;
    off += (bytes + 255) & ~(size_t)255;
    return o;
  };
  u16* xb     = (u16*)(ws + alloc((size_t)4096 * 2048 * 2));
  u16* wqkvb  = (u16*)(ws + alloc((size_t)3072 * 2048 * 2));
  u16* wob    = (u16*)(ws + alloc((size_t)2048 * 2048 * 2));
  u16* qkvraw = (u16*)(ws + alloc((size_t)4096 * 3072 * 2));  // later reused as ytmp
  u16* qr     = (u16*)(ws + alloc((size_t)4096 * 2048 * 2));
  u16* kr     = (u16*)(ws + alloc((size_t)4096 * 512 * 2));
  u16* vt     = (u16*)(ws + alloc((size_t)4096 * 512 * 2));
  float* ctab = (float*)(ws + alloc((size_t)2048 * 64 * 4));
  float* stab = (float*)(ws + alloc((size_t)2048 * 64 * 4));
  u16* ytmp = qkvraw;  // safe: qkvraw fully consumed before attn writes

  // 1/sqrt(128) * log2(e): Q scale folded so scores are in log2 domain
  const float sc_log2 = 0.12751744f;

  cvt_all<<<18432, 256, 0, stream>>>(x, wq, wk, wv, wo, xb, wqkvb, wob);
  rope_table<<<512, 256, 0, stream>>>(ctab, stab);

  // fused QKV projection: [4096,2048] x [3072,2048]^T -> [4096,3072]
  gemm8p<0><<<dim3(12, 16), 512, 0, stream>>>(xb, wqkvb, qkvraw, 4096, 3072, 2048);

  rope_norm<16><<<16384, 256, 0, stream>>>(qkvraw, qr, ctab, stab, gq, 3072, 0, sc_log2);
  rope_norm<4><<<4096, 256, 0, stream>>>(qkvraw, kr, ctab, stab, gk, 3072, 2048, 1.0f);
  transpose_v<<<dim3(64, 4, 8), 256, 0, stream>>>(qkvraw, vt);

  attn_kernel<<<dim3(512), 512, 0, stream>>>(qr, kr, vt, ytmp);

  // output projection (f32 out)
  gemm8p<1><<<dim3(8, 16), 512, 0, stream>>>(ytmp, wob, out, 4096, 2048, 2048);
}

// Round 9
// 198.353 us; speedup vs baseline: 1.1246x; 1.0669x over previous
//
#include <hip/hip_runtime.h>
#include <cstdint>
#include <cstddef>

typedef unsigned short u16;
typedef short bf16x8 __attribute__((ext_vector_type(8)));
typedef float f32x4 __attribute__((ext_vector_type(4)));

#define MFMA(a,b,c) __builtin_amdgcn_mfma_f32_16x16x32_bf16(a,b,c,0,0,0)

__device__ __forceinline__ u16 f2bf(float f) {
  unsigned u = __builtin_bit_cast(unsigned, f);
  u += 0x7fffu + ((u >> 16) & 1u);
  return (u16)(u >> 16);
}
__device__ __forceinline__ float bf2f(u16 b) {
  return __builtin_bit_cast(float, (unsigned)b << 16);
}
__device__ __forceinline__ float exp2_hw(float x) {
  float r;
  asm("v_exp_f32 %0, %1" : "=v"(r) : "v"(x));
  return r;
}
__device__ __forceinline__ void gl_lds16(const void* g, void* l) {
  __builtin_amdgcn_global_load_lds(
      (const __attribute__((address_space(1))) void*)g,
      (__attribute__((address_space(3))) void*)l, 16, 0, 0);
}
template <int N>
__device__ __forceinline__ void wait_vmcnt() {
  if constexpr (N == 0) asm volatile("s_waitcnt vmcnt(0)" ::: "memory");
  else if constexpr (N == 4) asm volatile("s_waitcnt vmcnt(4)" ::: "memory");
  else if constexpr (N == 6) asm volatile("s_waitcnt vmcnt(6)" ::: "memory");
  else if constexpr (N == 8) asm volatile("s_waitcnt vmcnt(8)" ::: "memory");
}

// ---------------- fused f32 -> bf16 convert for all 5 inputs ----------------
__global__ __launch_bounds__(256) void cvt_all(const float* __restrict__ x,
                                               const float* __restrict__ wq,
                                               const float* __restrict__ wk,
                                               const float* __restrict__ wv,
                                               const float* __restrict__ wo,
                                               u16* __restrict__ xb,
                                               u16* __restrict__ wqkvb,
                                               u16* __restrict__ wob) {
  int idx = (blockIdx.x * 256 + threadIdx.x) * 4;
  const float* src;
  u16* dst;
  if (idx < 8388608) { src = x + idx; dst = xb + idx; }
  else if (idx < 12582912) { src = wq + (idx - 8388608); dst = wqkvb + (idx - 8388608); }
  else if (idx < 13631488) { src = wk + (idx - 12582912); dst = wqkvb + (idx - 8388608); }
  else if (idx < 14680064) { src = wv + (idx - 13631488); dst = wqkvb + (idx - 8388608); }
  else if (idx < 18874368) { src = wo + (idx - 14680064); dst = wob + (idx - 14680064); }
  else return;
  float4 v = *(const float4*)src;
  ushort4 o = {f2bf(v.x), f2bf(v.y), f2bf(v.z), f2bf(v.w)};
  *(ushort4*)dst = o;
}

// ---------------- RoPE cos/sin table: [T=2048][64] f32 ----------------
__global__ __launch_bounds__(256) void rope_table(float* __restrict__ ctab,
                                                  float* __restrict__ stab) {
  int i = blockIdx.x * 256 + threadIdx.x;  // 0 .. 131071
  int t = i >> 6, f = i & 63;
  float inv_freq = powf(10000.0f, -(2.0f * f) / 128.0f);
  float ang = (float)t * inv_freq;
  ctab[i] = cosf(ang);
  stab[i] = sinf(ang);
}

// ---------------- deep-pipelined NT GEMM: BMxBN tile, BK=64 ----------------
// 2 LDS buffers (one full K-tile each), 8 waves. Per K-tile: 2x MFMA clusters,
// 2 barriers, 1 counted vmcnt (never 0 mid-loop). Stage of tile t+2 overwrites
// the buffer of tile t right after all reads landed.
template <int BM, int BN, int OUT_F32>
__global__ __launch_bounds__(512, 2) void gemm8p(const u16* __restrict__ A,
                                                 const u16* __restrict__ Bw,
                                                 void* __restrict__ Cout,
                                                 int M, int N, int K) {
  constexpr int WN = BN / 64;            // waves along N (4 or 2)
  constexpr int WM = 8 / WN;             // waves along M (2 or 4)
  constexpr int MSUB = BM / WM;          // rows per wave (128 or 64)
  constexpr int MF = MSUB / 16;          // A frags (8 or 4)
  constexpr int CHA = BM / 8;            // A chunks (1KB = 8 rows x 128B)
  constexpr int CPW = (CHA + BN / 8) / 8;  // chunks per wave per tile (8 or 6)

  __shared__ u16 As[2][BM * 64];  // 128B rows, 3-bit slot XOR swizzle
  __shared__ u16 Bs[2][BN * 64];
  const int tid = threadIdx.x;
  const int lane = tid & 63;
  const int wv = tid >> 6;
  const int l16 = lane & 15, lhi = lane >> 4;
  const int wm = wv / WN, wn = wv % WN;
  const int m0 = blockIdx.y * BM;
  const int n0 = blockIdx.x * BN;
  const int nt = K >> 6;

  const int srow8 = lane >> 3;                       // dest row within chunk
  const int scol = ((lane & 7) * 16) ^ (srow8 << 4); // pre-swizzled source col

  auto stage_tile = [&](int buf, int kt) {
#pragma unroll
    for (int c = 0; c < CPW; ++c) {
      int g = wv + 8 * c;
      if (g < CHA) {
        int row = m0 + g * 8 + srow8;
        const char* src = (const char*)A + ((size_t)row * K + (size_t)kt * 64) * 2 + scol;
        gl_lds16(src, (char*)As[buf] + g * 1024);
      } else {
        int gb = g - CHA;
        int row = n0 + gb * 8 + srow8;
        const char* src = (const char*)Bw + ((size_t)row * K + (size_t)kt * 64) * 2 + scol;
        gl_lds16(src, (char*)Bs[buf] + gb * 1024);
      }
    }
  };
  auto readA = [&](int buf, int mi, int kk) -> bf16x8 {
    int lr = wm * MSUB + mi * 16 + l16;
    return *(const bf16x8*)((const char*)As[buf] + lr * 128 +
                            ((kk * 64 + lhi * 16) ^ ((l16 & 7) << 4)));
  };
  auto readB = [&](int buf, int ni, int kk) -> bf16x8 {
    int lr = wn * 64 + ni * 16 + l16;
    return *(const bf16x8*)((const char*)Bs[buf] + lr * 128 +
                            ((kk * 64 + lhi * 16) ^ ((l16 & 7) << 4)));
  };

  f32x4 acc[MF][4] = {};

  stage_tile(0, 0);
  stage_tile(1, 1);
  wait_vmcnt<CPW>();               // tile0 landed; tile1's loads in flight
  __builtin_amdgcn_sched_barrier(0);
  __builtin_amdgcn_s_barrier();
  __builtin_amdgcn_sched_barrier(0);

  for (int t = 0; t < nt; ++t) {
    const int b = t & 1;
    // ---- P0: read kk0 frags, 32 MFMA; kk1 reads issued under the MFMA ----
    bf16x8 bf0[4], af0[MF];
#pragma unroll
    for (int ni = 0; ni < 4; ++ni) bf0[ni] = readB(b, ni, 0);
#pragma unroll
    for (int mi = 0; mi < MF; ++mi) af0[mi] = readA(b, mi, 0);
    __builtin_amdgcn_s_setprio(1);
#pragma unroll
    for (int mi = 0; mi < MF; ++mi)
#pragma unroll
      for (int ni = 0; ni < 4; ++ni)
        acc[mi][ni] = MFMA(af0[mi], bf0[ni], acc[mi][ni]);
    __builtin_amdgcn_s_setprio(0);
    bf16x8 bf1[4], af1[MF];
#pragma unroll
    for (int ni = 0; ni < 4; ++ni) bf1[ni] = readB(b, ni, 1);
#pragma unroll
    for (int mi = 0; mi < MF; ++mi) af1[mi] = readA(b, mi, 1);
    asm volatile("s_waitcnt lgkmcnt(0)" ::: "memory");  // all buf-b reads in regs
    __builtin_amdgcn_sched_barrier(0);
    __builtin_amdgcn_s_barrier();                        // all waves done with buf b
    __builtin_amdgcn_sched_barrier(0);
    if (t + 2 < nt) stage_tile(b, t + 2);                // safe overwrite
    __builtin_amdgcn_s_setprio(1);
#pragma unroll
    for (int mi = 0; mi < MF; ++mi)
#pragma unroll
      for (int ni = 0; ni < 4; ++ni)
        acc[mi][ni] = MFMA(af1[mi], bf1[ni], acc[mi][ni]);
    __builtin_amdgcn_s_setprio(0);
    if (t + 2 < nt) wait_vmcnt<CPW>();      // retire tile t+1; t+2 stays in flight
    else if (t + 1 < nt) wait_vmcnt<0>();   // tail
    __builtin_amdgcn_sched_barrier(0);
    __builtin_amdgcn_s_barrier();
    __builtin_amdgcn_sched_barrier(0);
  }

  // epilogue
#pragma unroll
  for (int mi = 0; mi < MF; ++mi)
#pragma unroll
    for (int ni = 0; ni < 4; ++ni) {
      int col = n0 + wn * 64 + ni * 16 + l16;
#pragma unroll
      for (int j = 0; j < 4; ++j) {
        int row = m0 + wm * MSUB + mi * 16 + lhi * 4 + j;
        float v = acc[mi][ni][j];
        if (OUT_F32)
          ((float*)Cout)[(size_t)row * N + col] = v;
        else
          ((u16*)Cout)[(size_t)row * N + col] = f2bf(v);
      }
    }
}

// ---------------- RoPE + L2 norm + gamma (vectorized: 4B/lane) ----------------
template <int NH>
__global__ __launch_bounds__(256) void rope_norm(const u16* __restrict__ raw,
                                                 u16* __restrict__ out,
                                                 const float* __restrict__ ctab,
                                                 const float* __restrict__ stab,
                                                 const float* __restrict__ gamma,
                                                 int stride, int coloff, float scale) {
  int gw = blockIdx.x * 4 + (threadIdx.x >> 6);
  int lane = threadIdx.x & 63;
  int h = gw & (NH - 1);
  int bt = gw / NH;               // 0..4095
  int t = bt & 2047, bb = bt >> 11;
  const u16* r = raw + (size_t)bt * stride + coloff + (size_t)h * 128;
  ushort2 own = *(const ushort2*)(r + 2 * lane);
  int pk = __shfl_xor(__builtin_bit_cast(int, own), 32);
  ushort2 par = __builtin_bit_cast(ushort2, pk);
  float x0 = bf2f(own.x), x1 = bf2f(own.y);
  float y0 = bf2f(par.x), y1 = bf2f(par.y);
  int f = (lane & 31) * 2;
  float2 c2 = *(const float2*)(ctab + t * 64 + f);
  float2 s2 = *(const float2*)(stab + t * 64 + f);
  bool hi = lane >= 32;
  float e0 = hi ? (x0 * c2.x + y0 * s2.x) : (x0 * c2.x - y0 * s2.x);
  float e1 = hi ? (x1 * c2.y + y1 * s2.y) : (x1 * c2.y - y1 * s2.y);
  float ss = e0 * e0 + e1 * e1;
#pragma unroll
  for (int off = 1; off < 64; off <<= 1) ss += __shfl_xor(ss, off);
  float inv = scale / (sqrtf(ss) + 1e-6f);
  float2 g2 = *(const float2*)(gamma + 2 * lane);
  size_t ob = (((size_t)(bb * NH + h)) * 2048 + t) * 128 + 2 * lane;
  ushort2 o = {f2bf(e0 * inv * g2.x), f2bf(e1 * inv * g2.y)};
  *(ushort2*)(out + ob) = o;
}

// ---------------- V transpose: qkv[B*T,3072] cols 2560.. -> [B, HK, 128, T] ----------------
__global__ __launch_bounds__(256) void transpose_v(const u16* __restrict__ qkv,
                                                   u16* __restrict__ vt) {
  __shared__ u16 tile[32][33];
  int t0 = blockIdx.x * 32, d0 = blockIdx.y * 32;
  int bh = blockIdx.z;
  int b = bh >> 2, hkk = bh & 3;
  int tx = threadIdx.x & 31, ty = threadIdx.x >> 5;  // ty 0..7
#pragma unroll
  for (int i = 0; i < 4; ++i) {
    int r = ty + i * 8;
    tile[r][tx] = qkv[((size_t)(b * 2048 + t0 + r)) * 3072 + 2560 + hkk * 128 + d0 + tx];
  }
  __syncthreads();
#pragma unroll
  for (int i = 0; i < 4; ++i) {
    int r = ty + i * 8;
    vt[((size_t)((b * 4 + hkk) * 128 + d0 + r)) * 2048 + t0 + tx] = tile[tx][r];
  }
}

// ---------------- flash attention, sliding window 1024, QBLK=128, KVBLK=64 ----------------
// 8 waves/block (512 thr), K+V double-buffered (swizzled) in LDS, counted-vmcnt
// gates (no vmcnt(0) drain mid-loop), log2-domain softmax with wave-shared base,
// rowsum via ones-MFMA, XCD-aware block remap.
__global__ __launch_bounds__(512, 4) void attn_kernel(const u16* __restrict__ Qr,
                                                      const u16* __restrict__ Kr,
                                                      const u16* __restrict__ Vt,
                                                      u16* __restrict__ Yt) {
  __shared__ u16 Ks[2][64 * 128];   // XOR-swizzled 256B rows (2x16KB)
  __shared__ u16 Vs[2][128 * 64];   // XOR-swizzled 128B rows, [d][s] (2x16KB)
  __shared__ u16 Ps[8][16 * 64];    // per-wave P, XOR-swizzled 128B rows (16KB)
  const int tid = threadIdx.x;
  const int lane = tid & 63;
  const int wv = tid >> 6;          // 0..7
  const int l16 = lane & 15, lhi = lane >> 4;
  const int work = (blockIdx.x & 7) * 64 + (blockIdx.x >> 3);
  const int q0b = (work & 15) << 7;     // q-tile * 128
  const int bh = work >> 4;             // 0..31
  const int b = bh >> 4, h = bh & 15;
  const int hk = h >> 2;
  const int q0w = q0b + wv * 16;

  const u16* qbase = Qr + (((size_t)bh) * 2048 + q0w + l16) * 128;
  bf16x8 qf[4];
#pragma unroll
  for (int dc = 0; dc < 4; ++dc)
    qf[dc] = *(const bf16x8*)(qbase + dc * 32 + lhi * 8);

  const char* kg = (const char*)(Kr + ((size_t)(b * 4 + hk)) * 2048 * 128);
  const u16* vg = Vt + ((size_t)(b * 4 + hk)) * 2048 * 128;  // [128][2048]

  auto stage = [&](int buf, int s0) {   // 4 gl_lds per wave
#pragma unroll
    for (int i = 0; i < 2; ++i) {
      int c = wv + 8 * i;
      int row = c * 4 + lhi;
      int srcb = (l16 * 16) ^ ((row & 7) << 4);
      gl_lds16(kg + (size_t)(s0 + row) * 256 + srcb, (char*)Ks[buf] + c * 1024);
    }
    int r8 = lane >> 3, c8 = lane & 7;
#pragma unroll
    for (int i = 0; i < 2; ++i) {
      int c = wv + 8 * i;
      int row = c * 8 + r8;
      int srcb = (c8 * 16) ^ ((r8 & 7) << 4);
      gl_lds16((const char*)(vg + (size_t)row * 2048 + s0) + srcb,
               (char*)Vs[buf] + c * 1024);
    }
  };

  const bf16x8 ones = {0x3F80, 0x3F80, 0x3F80, 0x3F80, 0x3F80, 0x3F80, 0x3F80, 0x3F80};
  float mbase = 0.f;                // wave-shared log2-domain base
  f32x4 lacc = {};
  f32x4 oacc[8] = {};

  int s_lo = q0b - 1024; if (s_lo < 0) s_lo = 0;
  const int nt = (q0b + 128 - s_lo) >> 6;

  stage(0, s_lo);
  int cur = 0;
  for (int it = 0; it < nt; ++it) {
    const int s0 = s_lo + (it << 6);
    // gate: buf cur's 4 loads retired; next tile's stay in flight
    if (it + 1 < nt) {
      stage(cur ^ 1, s0 + 64);
      wait_vmcnt<4>();
    } else {
      wait_vmcnt<0>();
    }
    __builtin_amdgcn_sched_barrier(0);
    __builtin_amdgcn_s_barrier();
    __builtin_amdgcn_sched_barrier(0);
    const bool skip = (q0w + 15 < s0) || (q0w - (s0 + 63) > 1024);
    if (!skip) {
      // QK^T (16 MFMA)
      f32x4 sacc[4] = {};
      const char* ksb = (const char*)Ks[cur];
      __builtin_amdgcn_s_setprio(1);
#pragma unroll
      for (int n = 0; n < 4; ++n) {
        int row = n * 16 + l16;
#pragma unroll
        for (int dc = 0; dc < 4; ++dc) {
          bf16x8 kf = *(const bf16x8*)(ksb + row * 256 +
                                       ((dc * 64 + lhi * 16) ^ ((l16 & 7) << 4)));
          sacc[n] = MFMA(qf[dc], kf, sacc[n]);
        }
      }
      __builtin_amdgcn_s_setprio(0);
      const bool domask = (q0w < s0 + 63) || (q0w + 15 - s0 > 1024);
      if (domask) {
#pragma unroll
        for (int n = 0; n < 4; ++n)
#pragma unroll
          for (int j = 0; j < 4; ++j) {
            int q = q0w + lhi * 4 + j;
            int s = s0 + n * 16 + l16;
            if ((unsigned)(q - s) > 1024u) sacc[n][j] = -INFINITY;
          }
      }
      float mt = sacc[0][0];
#pragma unroll
      for (int n = 0; n < 4; ++n)
#pragma unroll
        for (int j = 0; j < 4; ++j) mt = fmaxf(mt, sacc[n][j]);
#pragma unroll
      for (int off = 1; off < 64; off <<= 1) mt = fmaxf(mt, __shfl_xor(mt, off));
      if (mt > mbase + 8.f) {
        float sc2 = exp2_hw(mbase - mt);
#pragma unroll
        for (int j = 0; j < 4; ++j) lacc[j] *= sc2;
#pragma unroll
        for (int dt = 0; dt < 8; ++dt)
#pragma unroll
          for (int j = 0; j < 4; ++j) oacc[dt][j] *= sc2;
        mbase = mt;
      }
      char* psb = (char*)Ps[wv];
#pragma unroll
      for (int n = 0; n < 4; ++n)
#pragma unroll
        for (int j = 0; j < 4; ++j) {
          float p = exp2_hw(sacc[n][j] - mbase);
          int R = lhi * 4 + j;
          *(u16*)(psb + R * 128 + (((n * 16 + l16) * 2) ^ ((R & 7) << 4))) = f2bf(p);
        }
      bf16x8 pf[2];
#pragma unroll
      for (int kk = 0; kk < 2; ++kk)
        pf[kk] = *(const bf16x8*)(psb + l16 * 128 +
                                  ((kk * 64 + lhi * 16) ^ ((l16 & 7) << 4)));
      const char* vsb = (const char*)Vs[cur];
      __builtin_amdgcn_s_setprio(1);
      lacc = MFMA(pf[0], ones, lacc);
      lacc = MFMA(pf[1], ones, lacc);
#pragma unroll
      for (int dt = 0; dt < 8; ++dt) {
        int row = dt * 16 + l16;
#pragma unroll
        for (int kk = 0; kk < 2; ++kk) {
          bf16x8 vf = *(const bf16x8*)(vsb + row * 128 +
                                       ((kk * 64 + lhi * 16) ^ ((l16 & 7) << 4)));
          oacc[dt] = MFMA(pf[kk], vf, oacc[dt]);
        }
      }
      __builtin_amdgcn_s_setprio(0);
    }
    // trailing barrier: all waves' reads of buf cur consumed before next stage
    __builtin_amdgcn_sched_barrier(0);
    __builtin_amdgcn_s_barrier();
    __builtin_amdgcn_sched_barrier(0);
    cur ^= 1;
  }
#pragma unroll
  for (int j = 0; j < 4; ++j) {
    float inv = 1.0f / lacc[j];
    int q = q0w + lhi * 4 + j;
    size_t rowbase = ((size_t)(b * 2048 + q)) * 2048 + (size_t)h * 128;
#pragma unroll
    for (int dt = 0; dt < 8; ++dt)
      Yt[rowbase + dt * 16 + l16] = f2bf(oacc[dt][j] * inv);
  }
}

extern "C" void kernel_launch(void* const* d_in, const int* in_sizes, int n_in,
                              void* d_out, int out_size, void* d_ws, size_t ws_size,
                              hipStream_t stream) {
  (void)in_sizes; (void)n_in; (void)out_size; (void)ws_size;
  const float* x  = (const float*)d_in[0];
  const float* wq = (const float*)d_in[1];
  const float* wk = (const float*)d_in[2];
  const float* wv = (const float*)d_in[3];
  const float* wo = (const float*)d_in[4];
  const float* gq = (const float*)d_in[5];
  const float* gk = (const float*)d_in[6];
  float* out = (float*)d_out;
  char* ws = (char*)d_ws;

  size_t off = 0;
  auto alloc = [&](size_t bytes) {
    size_t o = off;
    off += (bytes + 255) & ~(size_t)255;
    return o;
  };
  u16* xb     = (u16*)(ws + alloc((size_t)4096 * 2048 * 2));
  u16* wqkvb  = (u16*)(ws + alloc((size_t)3072 * 2048 * 2));
  u16* wob    = (u16*)(ws + alloc((size_t)2048 * 2048 * 2));
  u16* qkvraw = (u16*)(ws + alloc((size_t)4096 * 3072 * 2));  // later reused as ytmp
  u16* qr     = (u16*)(ws + alloc((size_t)4096 * 2048 * 2));
  u16* kr     = (u16*)(ws + alloc((size_t)4096 * 512 * 2));
  u16* vt     = (u16*)(ws + alloc((size_t)4096 * 512 * 2));
  float* ctab = (float*)(ws + alloc((size_t)2048 * 64 * 4));
  float* stab = (float*)(ws + alloc((size_t)2048 * 64 * 4));
  u16* ytmp = qkvraw;  // safe: qkvraw fully consumed before attn writes

  // 1/sqrt(128) * log2(e): Q scale folded so scores are in log2 domain
  const float sc_log2 = 0.12751744f;

  cvt_all<<<18432, 256, 0, stream>>>(x, wq, wk, wv, wo, xb, wqkvb, wob);
  rope_table<<<512, 256, 0, stream>>>(ctab, stab);

  // fused QKV projection: [4096,2048] x [3072,2048]^T -> [4096,3072]
  gemm8p<256, 256, 0><<<dim3(12, 16), 512, 0, stream>>>(xb, wqkvb, qkvraw, 4096, 3072, 2048);

  rope_norm<16><<<16384, 256, 0, stream>>>(qkvraw, qr, ctab, stab, gq, 3072, 0, sc_log2);
  rope_norm<4><<<4096, 256, 0, stream>>>(qkvraw, kr, ctab, stab, gk, 3072, 2048, 1.0f);
  transpose_v<<<dim3(64, 4, 8), 256, 0, stream>>>(qkvraw, vt);

  attn_kernel<<<dim3(512), 512, 0, stream>>>(qr, kr, vt, ytmp);

  // output projection (f32 out): 256x128 tiles -> 256 blocks (1/CU)
  gemm8p<256, 128, 1><<<dim3(16, 16), 512, 0, stream>>>(ytmp, wob, out, 4096, 2048, 2048);
}